// Round 6
// baseline (288.272 us; speedup 1.0000x reference)
//
#include <hip/hip_runtime.h>
#include <utility>

#define EPS 1e-5f
typedef long long ll;
typedef float float4a __attribute__((ext_vector_type(4), aligned(4)));
typedef float float4v __attribute__((ext_vector_type(4)));

// ===================== compile-time path tables (RADIUS=5) =================
struct PathTables {
    int n;
    int dstY[34], dstX[34], plen[34];
    int py[34][11], px[34][11];
};
constexpr PathTables buildTables() {
    PathTables T{};
    int dirY[34] = {}, dirX[34] = {}; int nd = 0;
    for (int x = 1; x < 5; ++x) { dirY[nd] = 0; dirX[nd] = x; ++nd; }
    for (int y = 1; y < 5; ++y)
        for (int x = -4; x < 5; ++x)
            if (x * x + y * y < 25) { dirY[nd] = y; dirX[nd] = x; ++nd; }
    int L[34] = {}; int ppy[34][11] = {}, ppx[34][11] = {};
    for (int i = 0; i < nd; ++i) {
        int dy = dirY[i], dx = dirX[i], lsq = dy * dy + dx * dx, c = 0;
        int x0 = dx < 0 ? dx : 0, x1 = dx < 0 ? 0 : dx;
        for (int y = 0; y <= dy; ++y)
            for (int x = x0; x <= x1; ++x) {
                int num = dx * y - dy * x;
                if (num * num < lsq) { ppy[i][c] = y; ppx[i][c] = x; ++c; }
            }
        L[i] = c;
    }
    int lenOrder[16] = {}; int nl = 0;
    for (int i = 0; i < nd; ++i) {
        bool seen = false;
        for (int j = 0; j < nl; ++j) if (lenOrder[j] == L[i]) seen = true;
        if (!seen) lenOrder[nl++] = L[i];
    }
    int k = 0;
    for (int j = 0; j < nl; ++j)
        for (int i = 0; i < nd; ++i)
            if (L[i] == lenOrder[j]) {
                T.dstY[k] = dirY[i]; T.dstX[k] = dirX[i]; T.plen[k] = L[i];
                for (int l = 0; l < L[i]; ++l) { T.py[k][l] = ppy[i][l]; T.px[k][l] = ppx[i][l]; }
                ++k;
            }
    T.n = k;
    return T;
}
constexpr PathTables TAB = buildTables();

// ---- dst pair-groups: same row-extent, adjacent x; shared edge window -----
struct Groups {
    int ng;
    int nd[24], da[24], db[24];
    int ry[24];   // rows 0..ry
    int cb[24];   // first col (block-aligned): -4 or 0
    int ncb[24];  // number of 4-col blocks
};
constexpr Groups buildGroups() {
    Groups G{};
    int gi = 0;
    for (int y = 0; y <= 4; ++y) {
        int list[16]; int n = 0;
        for (int d = 0; d < TAB.n; ++d) if (TAB.dstY[d] == y) {
            int j = n++;
            while (j > 0 && TAB.dstX[list[j - 1]] > TAB.dstX[d]) { list[j] = list[j - 1]; --j; }
            list[j] = d;
        }
        for (int i = 0; i < n; i += 2) {
            int a = list[i];
            int b = (i + 1 < n) ? list[i + 1] : -1;
            G.nd[gi] = (b >= 0) ? 2 : 1; G.da[gi] = a; G.db[gi] = (b >= 0) ? b : a;
            int pmin = 0, pmax = 0;
            for (int j = 0; j < TAB.plen[a]; ++j) {
                int x = TAB.px[a][j]; if (x < pmin) pmin = x; if (x > pmax) pmax = x;
            }
            if (b >= 0) for (int j = 0; j < TAB.plen[b]; ++j) {
                int x = TAB.px[b][j]; if (x < pmin) pmin = x; if (x > pmax) pmax = x;
            }
            int cmax = pmax + 3;
            int b0 = (pmin < 0) ? -4 : 0;
            G.ry[gi] = y; G.cb[gi] = b0; G.ncb[gi] = (cmax - b0) / 4 + 1;
            ++gi;
        }
    }
    G.ng = gi;
    return G;
}
constexpr Groups GRP = buildGroups();

struct HTab { int v[3 * 34 + 2 * 34 * 11]; };
constexpr HTab buildHTab() {
    HTab h{};
    for (int d = 0; d < 34; ++d) {
        h.v[d] = TAB.dstY[d]; h.v[34 + d] = TAB.dstX[d]; h.v[68 + d] = TAB.plen[d];
        for (int j = 0; j < 11; ++j) {
            h.v[102 + d * 11 + j] = TAB.py[d][j];
            h.v[102 + 374 + d * 11 + j] = TAB.px[d][j];
        }
    }
    return h;
}
__constant__ HTab c_HT = buildHTab();
__constant__ Groups c_GRP = buildGroups();

// ===================== setup: zero state, extract offsets, verify ==========
__global__ void setup_kernel(const int* __restrict__ path_idx,
                             const int* __restrict__ src_idx,
                             const int* __restrict__ dst_idx,
                             const float* __restrict__ dtv,
                             int n_dst, int Lmax, int n_pos, int host_ok,
                             int* __restrict__ flag, int* __restrict__ counter,
                             double* __restrict__ acc,
                             int* __restrict__ offs, int* __restrict__ doffs) {
    int tid = threadIdx.x;
    if (tid == 0) { *flag = 0; *counter = 0; }
    if (tid < 8) acc[tid] = 0.0;
    int base0 = src_idx[0];
    for (int i = tid; i < n_dst * Lmax; i += 256)
        offs[i] = path_idx[(ll)i * n_pos] - base0;
    for (int i = tid; i < n_dst; i += 256)
        doffs[i] = dst_idx[(ll)i * n_pos] - base0;
    __syncthreads();
    if (!host_ok) { if (tid == 0) *flag = 1; return; }

    int bad = 0;
    if (tid < 34) {
        int d = tid;
        int Y = c_HT.v[d], X = c_HT.v[34 + d], L = c_HT.v[68 + d];
        if (doffs[d] != Y * 128 + X) bad = 1;
        if (dtv[d] != (float)Y || dtv[34 + d] != (float)X) bad = 1;
        for (int l = 0; l < 11; ++l) {                  // runtime path ⊆ table
            int o = offs[d * 11 + l]; int f = 0;
            for (int j = 0; j < L; ++j)
                if (o == c_HT.v[102 + d * 11 + j] * 128 + c_HT.v[102 + 374 + d * 11 + j]) f = 1;
            if (!f) bad = 1;
        }
        for (int j = 0; j < L; ++j) {                   // table ⊆ runtime path
            int o = c_HT.v[102 + d * 11 + j] * 128 + c_HT.v[102 + 374 + d * 11 + j]; int f = 0;
            for (int l = 0; l < 11; ++l) if (offs[d * 11 + l] == o) f = 1;
            if (!f) bad = 1;
        }
    }
    int nvec = n_pos / 4;
    for (int v = tid; v < nvec; v += 256) {
        int b0 = src_idx[4 * v];
        if (b0 & 3) bad = 1;
        if (src_idx[4 * v + 1] != b0 + 1 || src_idx[4 * v + 2] != b0 + 2 ||
            src_idx[4 * v + 3] != b0 + 3) bad = 1;
        int col = b0 & 127;
        if (col < 4 || col > 120) bad = 1;              // cols -4..+7 in row
        if (b0 + 4 * 128 + 7 >= 16384) bad = 1;         // rows 0..4 in image
    }
    if (bad) atomicOr(flag, 1);
}

// ===================== fast-path static compute ============================
template<int DI, int CB, int RY, int NC, int... Ls>
__device__ __forceinline__ void path_max4(const float (&w)[RY][NC], float (&m)[4],
                                          std::integer_sequence<int, Ls...>) {
    ((m[0] = fmaxf(m[0], w[TAB.py[DI][Ls]][TAB.px[DI][Ls] - CB + 0]),
      m[1] = fmaxf(m[1], w[TAB.py[DI][Ls]][TAB.px[DI][Ls] - CB + 1]),
      m[2] = fmaxf(m[2], w[TAB.py[DI][Ls]][TAB.px[DI][Ls] - CB + 2]),
      m[3] = fmaxf(m[3], w[TAB.py[DI][Ls]][TAB.px[DI][Ls] - CB + 3])), ...);
}

template<int DI, int CB, int RY, int NC>
__device__ __forceinline__ void proc_dst(const float (&w)[RY][NC],
    float4v a0, float4v a1,
    const float* __restrict__ lbB, const float* __restrict__ lbF,
    const float* __restrict__ lbN,
    const float* __restrict__ dq0b, const float* __restrict__ dq1b,
    int n_pos, float (&s)[8]) {
    constexpr int DY = TAB.dstY[DI], DX = TAB.dstX[DI];
    constexpr int DOFF = DY * 128 + DX;
    float m[4] = {-1e30f, -1e30f, -1e30f, -1e30f};
    path_max4<DI, CB>(w, m, std::make_integer_sequence<int, TAB.plen[DI]>{});
    float4v vb = *(const float4v*)(lbB + (ll)DI * n_pos);
    float4v vf = *(const float4v*)(lbF + (ll)DI * n_pos);
    float4v vn = *(const float4v*)(lbN + (ll)DI * n_pos);
    float4a c0 = *(const float4a*)(dq0b + DOFF);
    float4a c1 = *(const float4a*)(dq1b + DOFF);
#pragma unroll
    for (int k = 0; k < 4; ++k) {
        float mk = fmaxf(m[k], -80.f);
        // sig=1/(1+t), t=e^-m, u=1+t: posl=ln(u)-ln(t+eps*u), negl=ln(u)-ln(1+eps*u)
        float t  = __expf(-mk);
        float u  = 1.0f + t;
        float lu = __logf(u);
        float pl = lu - __logf(fmaf(EPS, u, t));
        float nl = lu - __logf(fmaf(EPS, u, 1.0f));
        s[5] += vb[k]; s[6] += vf[k]; s[7] += vn[k];
        s[0] = fmaf(vb[k], pl, s[0]);
        s[1] = fmaf(vf[k], pl, s[1]);
        s[2] = fmaf(vn[k], nl, s[2]);
        float q0 = a0[k] - c0[k];
        float q1 = a1[k] - c1[k];
        s[3] = fmaf(vf[k], fabsf(q0 - (float)DY) + fabsf(q1 - (float)DX), s[3]);
        s[4] = fmaf(vb[k], fabsf(q0) + fabsf(q1), s[4]);
    }
}

template<int G>
__device__ __forceinline__ void do_group(const float* __restrict__ eb,
    const float* __restrict__ dq,
    const float* __restrict__ lbB, const float* __restrict__ lbF,
    const float* __restrict__ lbN, int base, int n_pos, float (&s)[8]) {
    constexpr int RY = GRP.ry[G] + 1, NC = GRP.ncb[G] * 4, CB = GRP.cb[G];
    float w[RY][NC];
    const float* ew = eb + base + CB;     // 16B-aligned (base%4==0, CB%4==0)
#pragma unroll
    for (int r = 0; r < RY; ++r)
#pragma unroll
        for (int c = 0; c < NC / 4; ++c) {
            float4v t = *(const float4v*)(ew + r * 128 + c * 4);
            w[r][4 * c] = t[0]; w[r][4 * c + 1] = t[1];
            w[r][4 * c + 2] = t[2]; w[r][4 * c + 3] = t[3];
        }
    const float* dq0b = dq + base;
    const float* dq1b = dq + 16384 + base;
    float4v a0 = *(const float4v*)dq0b;
    float4v a1 = *(const float4v*)dq1b;
    proc_dst<GRP.da[G], CB>(w, a0, a1, lbB, lbF, lbN, dq0b, dq1b, n_pos, s);
    if constexpr (GRP.nd[G] == 2)
        proc_dst<GRP.db[G], CB>(w, a0, a1, lbB, lbF, lbN, dq0b, dq1b, n_pos, s);
}

template<int G>
__device__ __forceinline__ void run_group(int z, const float* __restrict__ eb,
    const float* __restrict__ dq,
    const float* __restrict__ lbB, const float* __restrict__ lbF,
    const float* __restrict__ lbN, int base, int n_pos, float (&s)[8]) {
    if (z == G) { do_group<G>(eb, dq, lbB, lbF, lbN, base, n_pos, s); return; }
    if constexpr (G + 1 < GRP.ng)
        run_group<G + 1>(z, eb, dq, lbB, lbF, lbN, base, n_pos, s);
}

// ===================== main fused kernel (+last-block finalize) ============
__launch_bounds__(256)
__global__ void loss_kernel(const float* __restrict__ edge, const float* __restrict__ dp,
    const float* __restrict__ bgl, const float* __restrict__ fgl,
    const float* __restrict__ ngl, const float* __restrict__ dtv,
    const int* __restrict__ src_idx, const int* __restrict__ offs,
    const int* __restrict__ doffs, const int* __restrict__ flag,
    int* __restrict__ counter, float* __restrict__ partials,
    int nblk, int n_pos, int Lmax, float* __restrict__ out) {
    int tid = threadIdx.x;
    int z = blockIdx.z, b = blockIdx.y;
    int bid = blockIdx.x + gridDim.x * (b + gridDim.y * z);
    float s[8] = {0.f, 0.f, 0.f, 0.f, 0.f, 0.f, 0.f, 0.f};
    int p0 = (blockIdx.x * 256 + tid) * 4;
    int bad = *flag;

    if (p0 < n_pos) {
        ll strideB = (ll)34 * n_pos;
        const float* lb = bgl + (ll)b * strideB + p0;
        const float* lf = fgl + (ll)b * strideB + p0;
        const float* ln = ngl + (ll)b * strideB + p0;
        const float* eb = edge + (ll)b * 16384;
        const float* dq = dp + (ll)b * 32768;
        if (!bad) {
            int base = src_idx[p0];
            run_group<0>(z, eb, dq, lb, lf, ln, base, n_pos, s);
        } else {
            int nd = c_GRP.nd[z];
            for (int j = 0; j < nd; ++j) {
                int d = j ? c_GRP.db[z] : c_GRP.da[z];
                int doff = doffs[d];
                float dt0 = dtv[d], dt1 = dtv[34 + d];
                for (int k = 0; k < 4; ++k) {
                    int p = p0 + k; if (p >= n_pos) break;
                    int bs = src_idx[p];
                    float m = -1e30f;
                    for (int l = 0; l < Lmax; ++l)
                        m = fmaxf(m, eb[bs + offs[d * Lmax + l]]);
                    m = fmaxf(m, -80.f);
                    float t = __expf(-m), u = 1.f + t, lu = __logf(u);
                    float pl = lu - __logf(fmaf(EPS, u, t));
                    float nl = lu - __logf(fmaf(EPS, u, 1.f));
                    float vb = lb[(ll)d * n_pos + k];
                    float vf = lf[(ll)d * n_pos + k];
                    float vn = ln[(ll)d * n_pos + k];
                    s[5] += vb; s[6] += vf; s[7] += vn;
                    s[0] = fmaf(vb, pl, s[0]); s[1] = fmaf(vf, pl, s[1]);
                    s[2] = fmaf(vn, nl, s[2]);
                    float q0 = dq[bs] - dq[bs + doff];
                    float q1 = dq[16384 + bs] - dq[16384 + bs + doff];
                    s[3] = fmaf(vf, fabsf(q0 - dt0) + fabsf(q1 - dt1), s[3]);
                    s[4] = fmaf(vb, fabsf(q0) + fabsf(q1), s[4]);
                }
            }
        }
    }

    // ---- block reduction ----
    __shared__ float red[4][8];
    __shared__ int s_last;
    if (tid == 0) s_last = 0;
    int lane = tid & 63, wv = tid >> 6;
#pragma unroll
    for (int i = 0; i < 8; ++i) {
        float v = s[i];
        for (int o = 32; o > 0; o >>= 1) v += __shfl_down(v, o);
        if (lane == 0) red[wv][i] = v;
    }
    __syncthreads();
    if (tid < 8) {
        float t = red[0][tid] + red[1][tid] + red[2][tid] + red[3][tid];
        __hip_atomic_store(&partials[(ll)bid * 8 + tid], t,
                           __ATOMIC_RELAXED, __HIP_MEMORY_SCOPE_AGENT);
    }
    if (tid == 0) {
        __threadfence();   // release partials (stores above are wave-0 program order)
        int old = __hip_atomic_fetch_add(counter, 1, __ATOMIC_ACQ_REL,
                                         __HIP_MEMORY_SCOPE_AGENT);
        if (old == nblk - 1) s_last = 1;
    }
    __syncthreads();

    // ---- last block reduces all partials and writes the scalar ----
    if (s_last) {
        __shared__ double sacc[8][33];
        int a = tid & 7, j0 = tid >> 3;
        double tot = 0.0;
        for (int j = j0; j < nblk; j += 32)
            tot += (double)__hip_atomic_load(&partials[(ll)j * 8 + a],
                                             __ATOMIC_RELAXED, __HIP_MEMORY_SCOPE_AGENT);
        sacc[a][j0] = tot;
        __syncthreads();
        if (tid < 8) {
            double T = 0.0;
            for (int j = 0; j < 32; ++j) T += sacc[tid][j];
            sacc[tid][32] = T;
        }
        __syncthreads();
        if (tid == 0) {
            double eps = 1e-5;
            double bg_pos = sacc[0][32] / (sacc[5][32] + eps);
            double fg_pos = sacc[1][32] / (sacc[6][32] + eps);
            double pos = 0.5 * bg_pos + 0.5 * fg_pos;
            double neg = sacc[2][32] / (sacc[7][32] + eps);
            double dfg = sacc[3][32] / (2.0 * sacc[6][32] + eps);
            double dbg = sacc[4][32] / (2.0 * sacc[5][32] + eps);
            out[0] = (float)(0.5 * (pos + neg) + 0.5 * (dfg + dbg));
        }
    }
}

// ===================== plan-B generic kernels (foreign shapes) =============
__launch_bounds__(256)
__global__ void loss_generic(const float* __restrict__ edge, const float* __restrict__ dp,
    const float* __restrict__ bgl, const float* __restrict__ fgl,
    const float* __restrict__ ngl, const float* __restrict__ dtv,
    const int* __restrict__ src_idx, const int* __restrict__ offs,
    const int* __restrict__ doffs,
    int n_dst, int n_pos, int HW, int Lmax, double* __restrict__ acc) {
    int d = blockIdx.z, b = blockIdx.y;
    int p = blockIdx.x * 256 + threadIdx.x;
    float s[8] = {0.f, 0.f, 0.f, 0.f, 0.f, 0.f, 0.f, 0.f};
    if (p < n_pos) {
        const float* eb = edge + (ll)b * HW;
        const float* dq = dp + (ll)b * 2 * HW;
        ll li = ((ll)b * n_dst + d) * n_pos + p;
        int bs = src_idx[p];
        float m = -1e30f;
        for (int l = 0; l < Lmax; ++l)
            m = fmaxf(m, eb[bs + offs[d * Lmax + l]]);
        m = fmaxf(m, -80.f);
        float t = __expf(-m), u = 1.f + t, lu = __logf(u);
        float pl = lu - __logf(fmaf(EPS, u, t));
        float nl = lu - __logf(fmaf(EPS, u, 1.f));
        float vb = bgl[li], vf = fgl[li], vn = ngl[li];
        s[5] = vb; s[6] = vf; s[7] = vn;
        s[0] = vb * pl; s[1] = vf * pl; s[2] = vn * nl;
        int doff = doffs[d];
        float q0 = dq[bs] - dq[bs + doff];
        float q1 = dq[HW + bs] - dq[HW + bs + doff];
        float dt0 = dtv[d], dt1 = dtv[n_dst + d];
        s[3] = vf * (fabsf(q0 - dt0) + fabsf(q1 - dt1));
        s[4] = vb * (fabsf(q0) + fabsf(q1));
    }
    __shared__ float red[4][8];
    int lane = threadIdx.x & 63, wv = threadIdx.x >> 6;
#pragma unroll
    for (int i = 0; i < 8; ++i) {
        float v = s[i];
        for (int o = 32; o > 0; o >>= 1) v += __shfl_down(v, o);
        if (lane == 0) red[wv][i] = v;
    }
    __syncthreads();
    if (threadIdx.x < 8) {
        float t = red[0][threadIdx.x] + red[1][threadIdx.x] +
                  red[2][threadIdx.x] + red[3][threadIdx.x];
        atomicAdd(&acc[threadIdx.x], (double)t);
    }
}

__global__ void finalize_atomic(const double* __restrict__ acc, float* __restrict__ out) {
    double eps = 1e-5;
    double bg_pos = acc[0] / (acc[5] + eps);
    double fg_pos = acc[1] / (acc[6] + eps);
    double pos = 0.5 * bg_pos + 0.5 * fg_pos;
    double neg = acc[2] / (acc[7] + eps);
    double dfg = acc[3] / (2.0 * acc[6] + eps);
    double dbg = acc[4] / (2.0 * acc[5] + eps);
    out[0] = (float)(0.5 * (pos + neg) + 0.5 * (dfg + dbg));
}

// ===================== host ================================================
extern "C" void kernel_launch(void* const* d_in, const int* in_sizes, int n_in,
                              void* d_out, int out_size, void* d_ws, size_t ws_size,
                              hipStream_t stream) {
    const float* edge = (const float*)d_in[0];
    const float* dp   = (const float*)d_in[1];
    const float* bgl  = (const float*)d_in[2];
    const float* fgl  = (const float*)d_in[3];
    const float* ngl  = (const float*)d_in[4];
    const float* dtv  = (const float*)d_in[5];
    const int* path_idx = (const int*)d_in[6];
    const int* src_idx  = (const int*)d_in[7];
    const int* dst_idx  = (const int*)d_in[8];

    int n_pos = in_sizes[7];
    int n_dst = in_sizes[8] / n_pos;
    int Lmax  = in_sizes[6] / (n_dst * n_pos);
    int B     = in_sizes[2] / (n_dst * n_pos);
    int HW    = in_sizes[0] / B;

    // ws layout
    int*    flag    = (int*)d_ws;
    int*    counter = flag + 1;
    double* acc     = (double*)((char*)d_ws + 64);
    int*    offs    = (int*)((char*)d_ws + 128);
    int*    doffs   = offs + n_dst * Lmax;
    char*   pend    = (char*)(doffs + n_dst);
    float*  partials = (float*)(((uintptr_t)pend + 255) & ~(uintptr_t)255);

    int nvb  = (n_pos / 4 + 255) / 256;
    int nblk = nvb * B * GRP.ng;
    size_t need = ((char*)(partials + (size_t)nblk * 8)) - (char*)d_ws;

    int host_ok = (n_dst == 34 && Lmax == 11 && n_pos == 14880 &&
                   HW == 16384 && (n_pos % 4) == 0 && need <= ws_size);

    setup_kernel<<<1, 256, 0, stream>>>(path_idx, src_idx, dst_idx, dtv,
                                        n_dst, Lmax, n_pos, host_ok,
                                        flag, counter, acc, offs, doffs);

    if (host_ok) {
        dim3 grid(nvb, B, GRP.ng);
        loss_kernel<<<grid, 256, 0, stream>>>(
            edge, dp, bgl, fgl, ngl, dtv, src_idx, offs, doffs,
            flag, counter, partials, nblk, n_pos, Lmax, (float*)d_out);
    } else {
        int pb = (n_pos + 255) / 256;
        loss_generic<<<dim3(pb, B, n_dst), 256, 0, stream>>>(
            edge, dp, bgl, fgl, ngl, dtv, src_idx, offs, doffs,
            n_dst, n_pos, HW, Lmax, acc);
        finalize_atomic<<<1, 1, 0, stream>>>(acc, (float*)d_out);
    }
}